// Round 16
// baseline (205.734 us; speedup 1.0000x reference)
//
#include <hip/hip_runtime.h>
#include <hip/hip_bf16.h>

#define BATCH 4096
#define NEXP  16
#define DIN   2048
#define DOUT  2048

#define BM 128
#define BN 64
#define NKT 64            // 64 k-tiles of 32 elements; processed as 32 pairs
#define NPAIR 32

#define WS_X_OFF   65536
#define PADROWS    4352   // 4096 + 16*16 worst-case padding
#define WS_X_BYTES ((size_t)PADROWS * 4096)
#define WS_W_OFF   (WS_X_OFF + WS_X_BYTES)
#define WS_W_BYTES ((size_t)NEXP * 128 * 65536)   // 134 MB: 2048 col-groups
#define NEED_ALL   (WS_W_OFF + WS_W_BYTES)
#define NEED_X     (WS_X_OFF + WS_X_BYTES)

typedef __attribute__((ext_vector_type(4))) float f32x4;
typedef __attribute__((ext_vector_type(8))) short bf16x8;

// --- Kernel 1: bucket sample indices by expert; write mxs/actions tail ---
// poffs[e]: 16-aligned padded offsets (fragment groups never cross experts).
__global__ void sort_kernel(const int* __restrict__ actions,
                            const float* __restrict__ mxs,
                            float* __restrict__ out_tail,
                            int* __restrict__ offs,     // [17]
                            int* __restrict__ poffs,    // [17]
                            int* __restrict__ sorted) {
    __shared__ int s_cnt[NEXP];
    __shared__ int s_cur[NEXP];
    const int tid = threadIdx.x;
    if (tid < NEXP) s_cnt[tid] = 0;
    __syncthreads();
    for (int i = tid; i < BATCH; i += blockDim.x) {
        int a = actions[i];
        atomicAdd(&s_cnt[a], 1);
        out_tail[i] = mxs[i];
        out_tail[BATCH + i] = (float)a;
    }
    __syncthreads();
    if (tid == 0) {
        int run = 0, prun = 0;
        for (int e = 0; e < NEXP; ++e) {
            offs[e] = run;  s_cur[e] = run;
            poffs[e] = prun;
            run += s_cnt[e];
            prun += (s_cnt[e] + 15) & ~15;
        }
        offs[NEXP] = run;
        poffs[NEXP] = prun;
    }
    __syncthreads();
    // Bucket order is atomics-dependent, but each sample's output is computed
    // independently with fixed k-order -> output bit-deterministic.
    for (int i = tid; i < BATCH; i += blockDim.x) {
        int e = actions[i];
        int pos = atomicAdd(&s_cur[e], 1);
        sorted[pos] = i;
    }
}

// fp32 pair -> packed bf16 (round-to-nearest-even): [bf16(x1) | bf16(x0)]
__device__ __forceinline__ unsigned rne2(float x0, float x1) {
    unsigned b0 = __float_as_uint(x0), b1 = __float_as_uint(x1);
    b0 = b0 + 0x7FFFu + ((b0 >> 16) & 1u);
    b1 = b1 + 0x7FFFu + ((b1 >> 16) & 1u);
    return (b1 & 0xFFFF0000u) | (b0 >> 16);
}

// W LDS tile layout for the FALLBACK kernel only (r15, measured 0-conflict).
__device__ __forceinline__ int lidxW(int r, int kb) {
    return r * 64 + ((kb ^ (r & 7)) << 3);
}

// --- Kernel 1b: X -> bf16 fragments, A-fragment-major ---
// Group = 16 padded rows of one expert = 64 KB: addr = grp*65536 + kt*1024
// + g*256 + slot*16. GEMM lane l reads grpbase + kt*1024 + l*16
// (slot = l&15 = row, g = l>>4 = k-quarter) -> its A-frag directly.
__global__ void xsplit_kernel(const float* __restrict__ xs,
                              const int* __restrict__ sorted,
                              const int* __restrict__ offs,
                              const int* __restrict__ poffs,
                              unsigned char* __restrict__ xws) {
    const int t = threadIdx.x;
    const int slot = t & 15;
    const int ktq = t >> 4;                 // 0..15, covers kt = ktq*4..+3
    const int p = blockIdx.x * 16 + slot;   // padded row index
    if (p >= poffs[NEXP]) return;
    int e = 0;
#pragma unroll
    for (int i = 1; i < NEXP; ++i)
        if (p >= poffs[i]) e = i;
    const int local = p - poffs[e];
    if (local >= offs[e + 1] - offs[e]) return;   // tail pad row
    const int src = sorted[offs[e] + local];
    const float* srow = xs + (size_t)src * DIN;
    unsigned char* gbase = xws + (size_t)blockIdx.x * 65536;
#pragma unroll
    for (int q = 0; q < 4; ++q) {
        const int kt = ktq * 4 + q;
        const float* s = srow + kt * 32;
        uint4 L[4];
#pragma unroll
        for (int j = 0; j < 4; ++j) {
            float4 a = *(const float4*)(s + 8 * j);
            float4 b = *(const float4*)(s + 8 * j + 4);
            L[j].x = rne2(a.x, a.y); L[j].y = rne2(a.z, a.w);
            L[j].z = rne2(b.x, b.y); L[j].w = rne2(b.z, b.w);
        }
        unsigned char* d = gbase + kt * 1024 + slot * 16;
#pragma unroll
        for (int g = 0; g < 4; ++g)
            *(uint4*)(d + g * 256) = L[g];
    }
}

// --- Kernel 1c: W -> bf16 fragments, B-fragment-major (mirror of xsplit) ---
// Group gw = e*128 + ng covers W rows (output cols) e*2048 + ng*16 .. +15.
// Same 64 KB group layout; GEMM lane l reads gwbase + kt*1024 + l*16.
// grid = 2048 blocks x 256 threads.
__global__ void wsplit_kernel(const float* __restrict__ W,
                              unsigned char* __restrict__ wws) {
    const int t = threadIdx.x;
    const int slot = t & 15;
    const int ktq = t >> 4;
    const int gw = blockIdx.x;              // e*128 + ng
    const float* srow = W + ((size_t)gw * 16 + slot) * DIN;  // row e*2048+ng*16+slot
    unsigned char* gbase = wws + (size_t)gw * 65536;
#pragma unroll
    for (int q = 0; q < 4; ++q) {
        const int kt = ktq * 4 + q;
        const float* s = srow + kt * 32;
        uint4 L[4];
#pragma unroll
        for (int j = 0; j < 4; ++j) {
            float4 a = *(const float4*)(s + 8 * j);
            float4 b = *(const float4*)(s + 8 * j + 4);
            L[j].x = rne2(a.x, a.y); L[j].y = rne2(a.z, a.w);
            L[j].z = rne2(b.x, b.y); L[j].w = rne2(b.z, b.w);
        }
        unsigned char* d = gbase + kt * 1024 + slot * 16;
#pragma unroll
        for (int g = 0; g < 4; ++g)
            *(uint4*)(d + g * 256) = L[g];
    }
}

// --- Kernel 2: grouped GEMM, pure bf16, ZERO LDS / ZERO barriers / ZERO asm.
// Both operands read directly as MFMA fragments from workspace; every wave
// fully independent (discriminating test of the serialization theory).
// Waves 4x1: wave owns rows [m0+wave*32,+32) x cols [n0,+64).
// 2-deep register double-buffer, static indexing (named bufs, rule #20).
// grid = (n=32 fastest, e=16, m=32); block 256.
__global__ __launch_bounds__(256, 3)
void gemm_direct(const unsigned char* __restrict__ xws,
                 const unsigned char* __restrict__ wws,
                 const float* __restrict__ bias,
                 const int* __restrict__ offs,
                 const int* __restrict__ poffs,
                 const int* __restrict__ sorted,
                 float* __restrict__ out) {
    const int e = blockIdx.y;
    const int start = offs[e];
    const int cnt = offs[e + 1] - start;
    const int m0 = blockIdx.z * BM;
    if (m0 >= cnt) return;
    const int n0 = blockIdx.x * BN;

    const int tid = threadIdx.x;
    const int lane = tid & 63;
    const int wave = tid >> 6;
    const int g = lane >> 4, rl = lane & 15;

    // A fragment group bases (clamped: clamped groups only hold rows >= cnt,
    // masked at the epilogue).
    const unsigned char* ab[2];
#pragma unroll
    for (int mi = 0; mi < 2; ++mi) {
        int prow = poffs[e] + m0 + wave * 32 + mi * 16;
        if (prow > PADROWS - 16) prow = PADROWS - 16;
        ab[mi] = xws + ((size_t)prow >> 4) * 65536 + (size_t)lane * 16;
    }
    // B fragment group bases: col-groups n0/16 + ni of expert e.
    const unsigned char* bb[4];
#pragma unroll
    for (int ni = 0; ni < 4; ++ni)
        bb[ni] = wws + ((size_t)(e * 128 + (n0 >> 4) + ni)) * 65536
                     + (size_t)lane * 16;

    f32x4 acc[2][4];
#pragma unroll
    for (int i = 0; i < 2; ++i)
#pragma unroll
        for (int j = 0; j < 4; ++j) acc[i][j] = (f32x4){0.f, 0.f, 0.f, 0.f};

    bf16x8 aA[2][2], aB[2][2];   // [mi][j-kt-within-pair]
    bf16x8 bA[2][4], bB[2][4];   // [j][ni]

#define LOADP(AX, BX, P) do {                                                  \
    const size_t _o = (size_t)(P) * 2048;                                      \
    _Pragma("unroll")                                                          \
    for (int _mi = 0; _mi < 2; ++_mi) {                                        \
        AX[_mi][0] = *(const bf16x8*)(ab[_mi] + _o);                           \
        AX[_mi][1] = *(const bf16x8*)(ab[_mi] + _o + 1024);                    \
    }                                                                          \
    _Pragma("unroll")                                                          \
    for (int _ni = 0; _ni < 4; ++_ni) {                                        \
        BX[0][_ni] = *(const bf16x8*)(bb[_ni] + _o);                           \
        BX[1][_ni] = *(const bf16x8*)(bb[_ni] + _o + 1024);                    \
    }                                                                          \
} while (0)

#define DOMFMA(AX, BX) do {                                                    \
    __builtin_amdgcn_s_setprio(1);                                             \
    _Pragma("unroll")                                                          \
    for (int _j = 0; _j < 2; ++_j)                                             \
        _Pragma("unroll")                                                      \
        for (int _mi = 0; _mi < 2; ++_mi)                                      \
            _Pragma("unroll")                                                  \
            for (int _ni = 0; _ni < 4; ++_ni)                                  \
                acc[_mi][_ni] = __builtin_amdgcn_mfma_f32_16x16x32_bf16(       \
                    AX[_mi][_j], BX[_j][_ni], acc[_mi][_ni], 0, 0, 0);         \
    __builtin_amdgcn_s_setprio(0);                                             \
} while (0)

    LOADP(aA, bA, 0);
    int pr = 0;
#pragma unroll 1
    for (int it = 0; it < NPAIR / 2; ++it) {
        LOADP(aB, bB, pr + 1);
        DOMFMA(aA, bA);
        LOADP(aA, bA, (pr + 2) & (NPAIR - 1));   // wrap: harmless reload
        DOMFMA(aB, bB);
        pr += 2;
    }
#undef LOADP
#undef DOMFMA

    // ---- epilogue: bias add + scatter rows (4x1 wave layout, r15-verified) --
    float bv[4];
#pragma unroll
    for (int ni = 0; ni < 4; ++ni)
        bv[ni] = bias[(size_t)e * DOUT + n0 + ni * 16 + rl];
#pragma unroll
    for (int mi = 0; mi < 2; ++mi) {
#pragma unroll
        for (int j = 0; j < 4; ++j) {
            int rm = m0 + wave * 32 + mi * 16 + g * 4 + j;
            if (rm < cnt) {
                int s = sorted[start + rm];
                float* orow = out + (size_t)s * DOUT + n0 + rl;
#pragma unroll
                for (int ni = 0; ni < 4; ++ni)
                    orow[ni * 16] = acc[mi][ni][j] + bv[ni];
            }
        }
    }
}

// --- Fallback: r15 kernel (proven, 164 us total) if ws too small for wws ---
__global__ __launch_bounds__(256, 3)
void gemm_lds(const unsigned char* __restrict__ xws,
              const float* __restrict__ W,
              const float* __restrict__ bias,
              const int* __restrict__ offs,
              const int* __restrict__ poffs,
              const int* __restrict__ sorted,
              float* __restrict__ out) {
    __shared__ __align__(16) unsigned short Wl[2][BN * 64];

    const int e = blockIdx.y;
    const int start = offs[e];
    const int cnt = offs[e + 1] - start;
    const int m0 = blockIdx.z * BM;
    if (m0 >= cnt) return;
    const int n0 = blockIdx.x * BN;

    const int tid = threadIdx.x;
    const int lane = tid & 63;
    const int wave = tid >> 6;
    const int g = lane >> 4, rl = lane & 15;

    const int swr = tid >> 2;
    const int wkq = tid & 3;
    const float* wsrc = W + ((size_t)e * DOUT + n0 + swr) * DIN + wkq * 16;

    const unsigned char* xb[2];
#pragma unroll
    for (int mi = 0; mi < 2; ++mi) {
        int prow = poffs[e] + m0 + wave * 32 + mi * 16;
        if (prow > PADROWS - 16) prow = PADROWS - 16;
        xb[mi] = xws + ((size_t)prow >> 4) * 65536 + (size_t)lane * 16;
    }

    f32x4 acc[2][4];
#pragma unroll
    for (int i = 0; i < 2; ++i)
#pragma unroll
        for (int j = 0; j < 4; ++j) acc[i][j] = (f32x4){0.f, 0.f, 0.f, 0.f};

    float4 pwA[4], pwB[4];
#pragma unroll
    for (int j = 0; j < 4; ++j) pwA[j] = *(const float4*)(wsrc + 0 * 64 + 4 * j);
#pragma unroll
    for (int j = 0; j < 4; ++j) pwB[j] = *(const float4*)(wsrc + 1 * 64 + 4 * j);
    bf16x8 axA[2][2], axB[2][2];
#pragma unroll
    for (int mi = 0; mi < 2; ++mi) {
        axA[mi][0] = *(const bf16x8*)(xb[mi]);
        axA[mi][1] = *(const bf16x8*)(xb[mi] + 1024);
    }
    {
        uint4 u0, u1;
        u0.x = rne2(pwA[0].x, pwA[0].y); u0.y = rne2(pwA[0].z, pwA[0].w);
        u0.z = rne2(pwA[1].x, pwA[1].y); u0.w = rne2(pwA[1].z, pwA[1].w);
        u1.x = rne2(pwA[2].x, pwA[2].y); u1.y = rne2(pwA[2].z, pwA[2].w);
        u1.z = rne2(pwA[3].x, pwA[3].y); u1.w = rne2(pwA[3].z, pwA[3].w);
        *(uint4*)&Wl[0][lidxW(swr, 2 * wkq)]     = u0;
        *(uint4*)&Wl[0][lidxW(swr, 2 * wkq + 1)] = u1;
#pragma unroll
        for (int j = 0; j < 4; ++j) pwA[j] = *(const float4*)(wsrc + 2 * 64 + 4 * j);
    }

    int pr = 0;

#define KSTEP(AXC, AXN, PWU, PAR) do {                                         \
    __builtin_amdgcn_sched_barrier(0);                                         \
    asm volatile("s_waitcnt lgkmcnt(0)");                                      \
    __builtin_amdgcn_sched_barrier(0);                                         \
    __builtin_amdgcn_s_barrier();                                              \
    __builtin_amdgcn_sched_barrier(0);                                         \
    bf16x8 bh[2][4];                                                           \
    _Pragma("unroll")                                                          \
    for (int j = 0; j < 2; ++j)                                                \
        _Pragma("unroll")                                                      \
        for (int ni = 0; ni < 4; ++ni)                                         \
            bh[j][ni] = *(const bf16x8*)&Wl[PAR][lidxW(ni * 16 + rl, j * 4 + g)]; \
    { int _kn = ((pr + 1) & (NPAIR - 1)) * 2;                                  \
      _Pragma("unroll")                                                        \
      for (int mi = 0; mi < 2; ++mi) {                                         \
          AXN[mi][0] = *(const bf16x8*)(xb[mi] + (size_t)_kn * 1024);          \
          AXN[mi][1] = *(const bf16x8*)(xb[mi] + (size_t)(_kn + 1) * 1024);    \
      } }                                                                      \
    { uint4 u0, u1;                                                            \
      u0.x = rne2(PWU[0].x, PWU[0].y); u0.y = rne2(PWU[0].z, PWU[0].w);        \
      u0.z = rne2(PWU[1].x, PWU[1].y); u0.w = rne2(PWU[1].z, PWU[1].w);        \
      u1.x = rne2(PWU[2].x, PWU[2].y); u1.y = rne2(PWU[2].z, PWU[2].w);        \
      u1.z = rne2(PWU[3].x, PWU[3].y); u1.w = rne2(PWU[3].z, PWU[3].w);        \
      *(uint4*)&Wl[PAR ^ 1][lidxW(swr, 2 * wkq)]     = u0;                     \
      *(uint4*)&Wl[PAR ^ 1][lidxW(swr, 2 * wkq + 1)] = u1; }                   \
    { int _k3 = (pr + 3) & (NPAIR - 1);                                        \
      _Pragma("unroll")                                                        \
      for (int j = 0; j < 4; ++j)                                              \
          PWU[j] = *(const float4*)(wsrc + (size_t)_k3 * 64 + 4 * j); }        \
    __builtin_amdgcn_s_setprio(1);                                             \
    _Pragma("unroll")                                                          \
    for (int j = 0; j < 2; ++j)                                                \
        _Pragma("unroll")                                                      \
        for (int mi = 0; mi < 2; ++mi)                                         \
            _Pragma("unroll")                                                  \
            for (int ni = 0; ni < 4; ++ni)                                     \
                acc[mi][ni] = __builtin_amdgcn_mfma_f32_16x16x32_bf16(AXC[mi][j], bh[j][ni], acc[mi][ni], 0, 0, 0); \
    __builtin_amdgcn_s_setprio(0);                                             \
    ++pr;                                                                      \
} while (0)

#pragma unroll 1
    for (int it = 0; it < NPAIR / 2; ++it) {
        KSTEP(axA, axB, pwB, 0);
        KSTEP(axB, axA, pwA, 1);
    }
#undef KSTEP

    float bv[4];
#pragma unroll
    for (int ni = 0; ni < 4; ++ni)
        bv[ni] = bias[(size_t)e * DOUT + n0 + ni * 16 + rl];
#pragma unroll
    for (int mi = 0; mi < 2; ++mi) {
#pragma unroll
        for (int j = 0; j < 4; ++j) {
            int rm = m0 + wave * 32 + mi * 16 + g * 4 + j;
            if (rm < cnt) {
                int s = sorted[start + rm];
                float* orow = out + (size_t)s * DOUT + n0 + rl;
#pragma unroll
                for (int ni = 0; ni < 4; ++ni)
                    orow[ni * 16] = acc[mi][ni][j] + bv[ni];
            }
        }
    }
}

extern "C" void kernel_launch(void* const* d_in, const int* in_sizes, int n_in,
                              void* d_out, int out_size, void* d_ws, size_t ws_size,
                              hipStream_t stream) {
    const float* xs      = (const float*)d_in[0];
    const float* mxs     = (const float*)d_in[1];
    const int*   actions = (const int*)d_in[2];
    const float* W       = (const float*)d_in[3];
    const float* b       = (const float*)d_in[4];
    float* out = (float*)d_out;

    int* ws_i   = (int*)d_ws;
    int* offs   = ws_i;          // [17]
    int* poffs  = ws_i + 20;     // [17]
    int* sorted = ws_i + 64;     // [BATCH]

    sort_kernel<<<1, 1024, 0, stream>>>(actions, mxs,
                                        out + (size_t)BATCH * DOUT,
                                        offs, poffs, sorted);

    unsigned char* xws = (unsigned char*)d_ws + WS_X_OFF;
    if (ws_size >= NEED_ALL) {
        unsigned char* wws = (unsigned char*)d_ws + WS_W_OFF;
        xsplit_kernel<<<PADROWS / 16, 256, 0, stream>>>(xs, sorted, offs, poffs, xws);
        wsplit_kernel<<<NEXP * 128, 256, 0, stream>>>(W, wws);
        dim3 grid(DOUT / BN, NEXP, BATCH / BM);
        gemm_direct<<<grid, 256, 0, stream>>>(xws, wws, b, offs, poffs, sorted, out);
    } else {
        // r15 proven path
        xsplit_kernel<<<PADROWS / 16, 256, 0, stream>>>(xs, sorted, offs, poffs, xws);
        dim3 grid(DOUT / BN, NEXP, BATCH / BM);
        gemm_lds<<<grid, 256, 0, stream>>>(xws, W, b, offs, poffs, sorted, out);
    }
}